// Round 7
// baseline (206.071 us; speedup 1.0000x reference)
//
#include <hip/hip_runtime.h>

#define HW 32
#define NPIX 1024      // 32*32
#define IMG 3072       // 3*32*32
#define IPB 4          // images per block: grid 2048 = 8 blocks/CU (wave-limit max)

typedef float vf4 __attribute__((ext_vector_type(4)));

// ---------------- threefry2x32 (exact JAX semantics) ----------------
__device__ __forceinline__ unsigned rotl32(unsigned x, int d) {
    return (x << d) | (x >> (32 - d));
}

struct UPair { unsigned a, b; };

__device__ __forceinline__ UPair threefry2x32(unsigned k0, unsigned k1,
                                              unsigned x0, unsigned x1) {
    unsigned k2 = k0 ^ k1 ^ 0x1BD11BDAu;
    x0 += k0; x1 += k1;
#define RND(r) { x0 += x1; x1 = rotl32(x1, (r)); x1 ^= x0; }
    RND(13) RND(15) RND(26) RND(6)
    x0 += k1; x1 += k2 + 1u;
    RND(17) RND(29) RND(16) RND(24)
    x0 += k2; x1 += k0 + 2u;
    RND(13) RND(15) RND(26) RND(6)
    x0 += k0; x1 += k1 + 3u;
    RND(17) RND(29) RND(16) RND(24)
    x0 += k1; x1 += k2 + 4u;
    RND(13) RND(15) RND(26) RND(6)
    x0 += k2; x1 += k0 + 5u;
#undef RND
    return {x0, x1};
}

__device__ __forceinline__ float bits_to_u01(unsigned bits) {
    return __uint_as_float((bits >> 9) | 0x3f800000u) - 1.0f;
}

// reference _reflect with lo=-0.5, span=32 — fmod-free (exact for pow-2 span)
__device__ __forceinline__ float reflect32(float c) {
    float t = fabsf(c + 0.5f);
    float flips = floorf(t * 0.03125f);
    float extra = fmaf(flips, -32.0f, t);
    float o = (((int)flips) & 1) ? (31.5f - extra) : (extra - 0.5f);
    return fminf(fmaxf(o, 0.0f), 31.0f);
}

// R3 per-image structure (best measured: 65.0 µs), made persistent over
// IPB=4 images with register prefetch of the next image's 12 global loads
// issued during the current image's compute. Only image 0 of each block
// pays HBM entry latency; images 1..3 find their data already in VGPRs.
// Params via lane-RNG + __shfl broadcast (no LDS, no cross-image races).
// STRIDED ownership: thread t owns column x=t&31, rows y=(t>>5)+8i ->
// every linear LDS vf4 access is conflict-free b128 (R3-verified).
__global__ __launch_bounds__(256) void aug_kernel(
    const float* __restrict__ xin, const float* __restrict__ aff,
    const int* __restrict__ apply_crop, float* __restrict__ out, int B) {
    __shared__ vf4 buf[NPIX];

    const int t = threadIdx.x;         // 0..255
    const int x = t & 31;              // fixed column per thread
    const int yr = t >> 5;             // row base; y_i = yr + 8*i
    const int lane = t & 63;
    const bool do_crop = (apply_crop[0] != 0);
    const size_t OUT_IMG = (size_t)B * IMG;
    const int img0 = blockIdx.x * IPB;

    // ---- image-independent per-thread geometry (hoisted) ----
    float dxv = fmaxf(fmaf((float)x, 0.78125f, -0.109375f), 0.0f);
    const int q0c = (int)dxv; const float lxc = dxv - (float)q0c;
    const int q1c = min(q0c + 1, 24);
    const float omxc = 1.0f - lxc;
    const float xn = (float)x * 0.0625f - 0.96875f;
    int i0a[4], i1a[4]; float lya[4], yna[4];
#pragma unroll
    for (int i = 0; i < 4; ++i) {
        int yi = yr + 8 * i;
        float dy = fmaxf(fmaf((float)yi, 0.78125f, -0.109375f), 0.0f);
        i0a[i] = (int)dy; lya[i] = dy - (float)i0a[i];
        i1a[i] = min(i0a[i] + 1, 24);
        yna[i] = (float)yi * 0.0625f - 0.96875f;
    }

    // ---- prologue: image 0 global loads (planar, lane-stride-1) ----
    float g0[4], g1[4], g2[4];
    {
        const float* src = xin + (size_t)img0 * IMG;
#pragma unroll
        for (int i = 0; i < 4; ++i) {
            int p = t + 256 * i;
            g0[i] = src[p]; g1[i] = src[NPIX + p]; g2[i] = src[2 * NPIX + p];
        }
    }

    for (int k = 0; k < IPB; ++k) {
        const int b = img0 + k;
        if (b >= B) break;                       // block-uniform

        // ---- per-image params: lanes 0..9 compute, __shfl broadcast ----
        // jax_threefry_partitionable: ks[j] = threefry(0,42, 0,j);
        // bits(key,b) = r.a^r.b, r = threefry(key,0,b);
        // randint: child k2 = threefry(key,0,1), val = bits(k2,b) & 7.
        float fval = 0.0f; int ival = 0;
        if (lane < 10) {
            UPair K = threefry2x32(0u, 42u, 0u, (unsigned)lane);
            if (lane < 2) {
                UPair k2 = threefry2x32(K.a, K.b, 0u, 1u);
                UPair r = threefry2x32(k2.a, k2.b, 0u, (unsigned)b);
                ival = (int)((r.a ^ r.b) & 7u);
            } else {
                UPair r = threefry2x32(K.a, K.b, 0u, (unsigned)b);
                float u = bits_to_u01(r.a ^ r.b);
                if      (lane == 2) ival = (u < 0.5f);
                else if (lane == 3) fval = 1.0f + (u - 0.5f) * 0.8f;
                else if (lane == 4) fval = 1.0f + (u - 0.5f) * 0.8f;
                else if (lane == 5) fval = 1.0f + (u - 0.5f) * 0.8f;
                else if (lane == 6) ival = (u < 0.5f);
                else if (lane == 7) ival = (u < 0.2f);
                else if (lane == 8) ival = (u < 0.5f);
                else                ival = (u < 0.1f);
            }
        }
        const int top  = __shfl(ival, 0), left = __shfl(ival, 1);
        const int flip = __shfl(ival, 2), hue  = __shfl(ival, 6);
        const int gray = __shfl(ival, 7), blur = __shfl(ival, 8);
        const int solar = __shfl(ival, 9);
        const float br   = __shfl(fval, 3);
        const float ctsa = __shfl(fval, 4) * __shfl(fval, 5); // contrast keeps mean
        const float th0 = aff[b * 6 + 0], th1 = aff[b * 6 + 1], th2 = aff[b * 6 + 2];
        const float th3 = aff[b * 6 + 3], th4 = aff[b * 6 + 4], th5 = aff[b * 6 + 5];

        // ---- stage (denorm) from prefetched regs ----
#pragma unroll
        for (int i = 0; i < 4; ++i) {
            vf4 v;
            v.x = fmaf(g0[i], 0.2675f, 0.5071f);
            v.y = fmaf(g1[i], 0.2565f, 0.4867f);
            v.z = fmaf(g2[i], 0.2761f, 0.4408f);
            v.w = 0.0f;
            buf[t + 256 * i] = v;
        }

        // ---- prefetch image k+1 (overlaps this image's entire compute) ----
        if (k + 1 < IPB && b + 1 < B) {
            const float* src = xin + (size_t)(b + 1) * IMG;
#pragma unroll
            for (int i = 0; i < 4; ++i) {
                int p = t + 256 * i;
                g0[i] = src[p]; g1[i] = src[NPIX + p]; g2[i] = src[2 * NPIX + p];
            }
        }

        // ---- passthrough outputs ----
        if (t == 0) out[OUT_IMG + b] = flip ? 1.0f : 0.0f;
        if (t < 6)  out[OUT_IMG + (size_t)B + (size_t)b * 6 + t] = aff[b * 6 + t];

        __syncthreads();   // (1) stage visible

        float cx[4], cy[4], cz[4];

        // ---- crop-resize: read phase (regs) | BAR | write-back | BAR ----
        if (do_crop) {
            const int c0 = left + q0c, c1 = left + q1c;
#pragma unroll
            for (int i = 0; i < 4; ++i) {
                int r0 = (top + i0a[i]) << 5, r1 = (top + i1a[i]) << 5;
                float ly = lya[i], omy = 1.0f - ly;
                float w00 = omy * omxc, w01 = omy * lxc;
                float w10 = ly * omxc, w11 = ly * lxc;
                vf4 t00 = buf[r0 + c0], t01 = buf[r0 + c1];
                vf4 t10 = buf[r1 + c0], t11 = buf[r1 + c1];
                cx[i] = fmaf(t00.x, w00, fmaf(t01.x, w01, fmaf(t10.x, w10, t11.x * w11)));
                cy[i] = fmaf(t00.y, w00, fmaf(t01.y, w01, fmaf(t10.y, w10, t11.y * w11)));
                cz[i] = fmaf(t00.z, w00, fmaf(t01.z, w01, fmaf(t10.z, w10, t11.z * w11)));
            }
            __syncthreads();   // all reads done before in-place overwrite
#pragma unroll
            for (int i = 0; i < 4; ++i) {
                vf4 v; v.x = cx[i]; v.y = cy[i]; v.z = cz[i]; v.w = 0.0f;
                buf[t + 256 * i] = v;
            }
            __syncthreads();
        }

        // ---- grid sample (flip folded) + fused color chain (regs) ----
#pragma unroll
        for (int i = 0; i < 4; ++i) {
            float gx = fmaf(th0, xn, fmaf(th1, yna[i], th2));
            float gy = fmaf(th3, xn, fmaf(th4, yna[i], th5));
            float ix = reflect32(fmaf(gx, 16.0f, 15.5f));
            float iy = reflect32(fmaf(gy, 16.0f, 15.5f));
            float fy = floorf(iy), fx = floorf(ix);
            float wy = iy - fy, wx = ix - fx;
            int y0 = (int)fy; int y1 = min(y0 + 1, 31);
            int x0 = (int)fx; int x1 = min(x0 + 1, 31);
            if (flip) { x0 = 31 - x0; x1 = 31 - x1; }
            int r0 = y0 << 5, r1 = y1 << 5;
            float omy = 1.0f - wy, omx = 1.0f - wx;
            float w00 = omy * omx, w01 = omy * wx;
            float w10 = wy * omx, w11 = wy * wx;
            vf4 t00 = buf[r0 + x0], t01 = buf[r0 + x1];
            vf4 t10 = buf[r1 + x0], t11 = buf[r1 + x1];
            float ch0 = fmaf(t00.x, w00, fmaf(t01.x, w01, fmaf(t10.x, w10, t11.x * w11)));
            float ch1 = fmaf(t00.y, w00, fmaf(t01.y, w01, fmaf(t10.y, w10, t11.y * w11)));
            float ch2 = fmaf(t00.z, w00, fmaf(t01.z, w01, fmaf(t10.z, w10, t11.z * w11)));
            ch0 *= br; ch1 *= br; ch2 *= br;
            float g = (ch0 + ch1 + ch2) * (1.0f / 3.0f);
            ch0 = fmaf(ch0 - g, ctsa, g);
            ch1 = fmaf(ch1 - g, ctsa, g);
            ch2 = fmaf(ch2 - g, ctsa, g);
            if (hue) { float tmp = ch0; ch0 = ch2; ch2 = tmp; }
            if (gray) { ch0 = ch1 = ch2 = g; }
            cx[i] = ch0; cy[i] = ch1; cz[i] = ch2;
        }

        // ---- blur: H-pass via lane shuffles (x±1 = lane±1), V via LDS ----
        if (blur) {
            __syncthreads();   // all sample reads done before overwrite
            const int tl = t - 1, tr = t + 1;
            float hx[4], hy[4], hz[4];
#pragma unroll
            for (int i = 0; i < 4; ++i) {
                float v, lf, rt;
                v = cx[i]; lf = __shfl(v, tl); rt = __shfl(v, tr);
                if (x == 0) lf = v;  if (x == 31) rt = v;
                hx[i] = lf + v + rt;
                v = cy[i]; lf = __shfl(v, tl); rt = __shfl(v, tr);
                if (x == 0) lf = v;  if (x == 31) rt = v;
                hy[i] = lf + v + rt;
                v = cz[i]; lf = __shfl(v, tl); rt = __shfl(v, tr);
                if (x == 0) lf = v;  if (x == 31) rt = v;
                hz[i] = lf + v + rt;
            }
#pragma unroll
            for (int i = 0; i < 4; ++i) {
                vf4 v; v.x = hx[i]; v.y = hy[i]; v.z = hz[i]; v.w = 0.0f;
                buf[t + 256 * i] = v;
            }
            __syncthreads();
#pragma unroll
            for (int i = 0; i < 4; ++i) {
                int yi = yr + 8 * i;
                vf4 up = buf[(max(yi - 1, 0) << 5) + x];
                vf4 dn = buf[(min(yi + 1, 31) << 5) + x];
                cx[i] = (up.x + hx[i] + dn.x) * (1.0f / 9.0f);
                cy[i] = (up.y + hy[i] + dn.y) * (1.0f / 9.0f);
                cz[i] = (up.z + hz[i] + dn.z) * (1.0f / 9.0f);
            }
        }

        // ---- solarize + clip + renorm + non-temporal planar stores ----
        {
            const float INV0 = 1.0f / 0.2675f, INV1 = 1.0f / 0.2565f, INV2 = 1.0f / 0.2761f;
            float* o = out + (size_t)b * IMG;
#pragma unroll
            for (int i = 0; i < 4; ++i) {
                int p = t + 256 * i;
                float r0v = cx[i], r1v = cy[i], r2v = cz[i];
                if (solar) {
                    if (r0v > 0.5f) r0v = 1.0f - r0v;
                    if (r1v > 0.5f) r1v = 1.0f - r1v;
                    if (r2v > 0.5f) r2v = 1.0f - r2v;
                }
                r0v = fminf(fmaxf(r0v, 0.0f), 1.0f);
                r1v = fminf(fmaxf(r1v, 0.0f), 1.0f);
                r2v = fminf(fmaxf(r2v, 0.0f), 1.0f);
                __builtin_nontemporal_store((r0v - 0.5071f) * INV0, o + p);
                __builtin_nontemporal_store((r1v - 0.4867f) * INV1, o + NPIX + p);
                __builtin_nontemporal_store((r2v - 0.4408f) * INV2, o + 2 * NPIX + p);
            }
        }

        // WAR guard: next iteration's stage overwrites buf, which this
        // image's sample/blur reads may still be using in other waves.
        if (k + 1 < IPB && b + 1 < B) __syncthreads();
    }
}

extern "C" void kernel_launch(void* const* d_in, const int* in_sizes, int n_in,
                              void* d_out, int out_size, void* d_ws, size_t ws_size,
                              hipStream_t stream) {
    const float* x = (const float*)d_in[0];
    const float* aff = (const float*)d_in[1];
    const int* ac = (const int*)d_in[2];
    float* out = (float*)d_out;
    int B = in_sizes[0] / IMG;
    int grid = (B + IPB - 1) / IPB;
    aug_kernel<<<dim3(grid), dim3(256), 0, stream>>>(x, aff, ac, out, B);
}